// Round 5
// baseline (132.224 us; speedup 1.0000x reference)
//
#include <hip/hip_runtime.h>

#define B_SZ   32
#define T_LEN  160000
#define NFFT   1024
#define HOP    320
#define FRAMES 501
#define NBINS  513
#define PADL   512

#define MROWS_BF  1024                    // interleaved cos/sin rows staged as bf16 (bins 0..511)
#define XP_STRIDE 164864                  // padded per-batch xp length (elements)
#define WS_XP_OFF (MROWS_BF * NFFT)       // ushort-element offset of xp region in ws
#define XP_G8_PB  (XP_STRIDE / 8)         // 20608 8-elem groups per batch

// prep-kernel block ranges
#define PB_BASIS  512                     // 512 blocks  : basis convert (131072 thr x 8 elems)
#define PB_XP     2576                    // 2576 blocks : xp convert    (659456 thr x 8 elems)
#define PB_BIN512 4012                    // 4012 blocks : bin512        (16048 waves >= 16032 dots)
#define PREP_BLOCKS (PB_BASIS + PB_XP + PB_BIN512)

typedef __bf16 bf16x8  __attribute__((ext_vector_type(8)));
typedef float  floatx4 __attribute__((ext_vector_type(4)));

__device__ __forceinline__ unsigned short f2bf(float f) {
    unsigned u = __builtin_bit_cast(unsigned, f);
    u += 0x7FFFu + ((u >> 16) & 1u);      // round-to-nearest-even
    return (unsigned short)(u >> 16);
}

__device__ __forceinline__ void gl_lds16(const void* g, void* l) {
    __builtin_amdgcn_global_load_lds(
        (const __attribute__((address_space(1))) unsigned int*)g,
        (__attribute__((address_space(3))) unsigned int*)l, 16, 0, 0);
}

// ---- fused prep: basis->bf16 (interleaved rows) | x->padded bf16 xp | bin512 fp32 ----
__global__ void stft_prep(const float* __restrict__ x,
                          const float* __restrict__ basis,
                          unsigned short* __restrict__ basisb,
                          unsigned short* __restrict__ xpb,
                          float* __restrict__ out) {
    const int blk = blockIdx.x;
    const int tid = threadIdx.x;

    if (blk < PB_BASIS) {
        // basis fp32 [1026][1024] -> bf16 [1024][1024], dst row 2j=cos_j, 2j+1=sin_j
        const int gid = blk * 256 + tid;          // 8 elems per thread, exact cover
        const int row = gid >> 7;                 // 0..1023
        const int col = (gid & 127) * 8;
        const int j = row >> 1, c = row & 1;
        const float* src = basis + (size_t)(j + c * NBINS) * NFFT + col;
        const float4 v0 = *(const float4*)(src);
        const float4 v1 = *(const float4*)(src + 4);
        ushort4 o0, o1;
        o0.x = f2bf(v0.x); o0.y = f2bf(v0.y); o0.z = f2bf(v0.z); o0.w = f2bf(v0.w);
        o1.x = f2bf(v1.x); o1.y = f2bf(v1.y); o1.z = f2bf(v1.z); o1.w = f2bf(v1.w);
        unsigned short* d = basisb + ((size_t)row << 10) + col;
        *(ushort4*)(d)     = o0;
        *(ushort4*)(d + 4) = o1;
    } else if (blk < PB_BASIS + PB_XP) {
        // x fp32 -> bf16 padded signal per batch: [512 zeros][x][zeros to XP_STRIDE]
        const int i   = (blk - PB_BASIS) * 256 + tid;   // 0..659455, exact cover
        const int b   = i / XP_G8_PB;
        const int pos = (i - b * XP_G8_PB) * 8;         // boundaries (512,160512) are %8==0
        ushort4 o0 = {0,0,0,0}, o1 = {0,0,0,0};
        if (pos >= PADL && pos < T_LEN + PADL) {
            const float* src = x + (size_t)b * T_LEN + (pos - PADL);
            const float4 v0 = *(const float4*)(src);
            const float4 v1 = *(const float4*)(src + 4);
            o0.x = f2bf(v0.x); o0.y = f2bf(v0.y); o0.z = f2bf(v0.z); o0.w = f2bf(v0.w);
            o1.x = f2bf(v1.x); o1.y = f2bf(v1.y); o1.z = f2bf(v1.z); o1.w = f2bf(v1.w);
        }
        unsigned short* d = xpb + (size_t)b * XP_STRIDE + pos;
        *(ushort4*)(d)     = o0;
        *(ushort4*)(d + 4) = o1;
    } else {
        // bin 512: real = cos_512 . frame in fp32 straight from x; imag = 0
        const int lane = tid & 63;
        const int d    = (blk - PB_BASIS - PB_XP) * 4 + (tid >> 6);  // wave-dot id
        if (d >= B_SZ * FRAMES) return;                              // wave-uniform
        const int b = d / FRAMES;
        const int f = d - b * FRAMES;
        const float* br = basis + (size_t)512 * NFFT + lane * 16;
        const float* xb = x + (size_t)b * T_LEN;
        const int base = f * HOP - PADL + lane * 16;
        float sum = 0.f;
        #pragma unroll
        for (int c = 0; c < 4; ++c) {
            const int xi = base + c * 4;
            const float4 bv = *(const float4*)(br + c * 4);
            float4 v;
            if (xi >= 0 && xi + 3 < T_LEN) {
                v = *(const float4*)(xb + xi);
            } else {
                v.x = (xi + 0 >= 0 && xi + 0 < T_LEN) ? xb[xi + 0] : 0.f;
                v.y = (xi + 1 >= 0 && xi + 1 < T_LEN) ? xb[xi + 1] : 0.f;
                v.z = (xi + 2 >= 0 && xi + 2 < T_LEN) ? xb[xi + 2] : 0.f;
                v.w = (xi + 3 >= 0 && xi + 3 < T_LEN) ? xb[xi + 3] : 0.f;
            }
            sum += bv.x * v.x + bv.y * v.y + bv.z * v.z + bv.w * v.w;
        }
        #pragma unroll
        for (int off = 32; off >= 1; off >>= 1) sum += __shfl_down(sum, off);
        if (lane == 0) {
            float2 val; val.x = sum; val.y = 0.f;
            *(float2*)(out + (((size_t)b * NBINS + 512) * FRAMES + f) * 2) = val;
        }
    }
}

// ---- MFMA GEMM (verified R3 structure, unchanged): C[m][f] = sum_k A[m][k]*xp[f*HOP+k] ----
__launch_bounds__(256, 4)
__global__ void stft_mfma_kernel(const unsigned short* __restrict__ basisb,
                                 const unsigned short* __restrict__ xpb,
                                 float* __restrict__ out) {
    __shared__ unsigned short lsA[2][128 * 32];
    __shared__ unsigned short lsB[2][128 * 32];

    const int tid  = threadIdx.x;
    const int lane = tid & 63;
    const int w    = tid >> 6;
    const int wm   = w & 1;
    const int wn   = w >> 1;
    const int r0   = lane & 15;
    const int quad = lane >> 4;

    const int fg0 = blockIdx.x * 128;
    const int mg0 = blockIdx.y * 128;
    const int b   = blockIdx.z;

    const unsigned short* xpbb = xpb + (size_t)b * XP_STRIDE;

    floatx4 acc[4][4] = {};

    for (int k0 = 0; k0 < NFFT; k0 += 64) {
        __syncthreads();

        #pragma unroll
        for (int h = 0; h < 2; ++h) {
            #pragma unroll
            for (int i = 0; i < 2; ++i) {
                const int idx = i * 256 + tid;       // 0..511
                const int mm  = idx >> 2;            // 0..127
                const int ko  = (idx & 3) * 8;       // 0,8,16,24
                gl_lds16(basisb + (((size_t)(mg0 + mm)) << 10) + k0 + h * 32 + ko,
                         &lsA[h][idx * 8]);
                gl_lds16(xpbb + (size_t)(fg0 + mm) * HOP + k0 + h * 32 + ko,
                         &lsB[h][idx * 8]);
            }
        }
        __syncthreads();

        #pragma unroll
        for (int h = 0; h < 2; ++h) {
            bf16x8 af[4], bf[4];
            #pragma unroll
            for (int mt = 0; mt < 4; ++mt)
                af[mt] = *(const bf16x8*)(&lsA[h][(wm * 64 + mt * 16 + r0) * 32 + quad * 8]);
            #pragma unroll
            for (int nt = 0; nt < 4; ++nt)
                bf[nt] = *(const bf16x8*)(&lsB[h][(wn * 64 + nt * 16 + r0) * 32 + quad * 8]);

            #pragma unroll
            for (int mt = 0; mt < 4; ++mt)
                #pragma unroll
                for (int nt = 0; nt < 4; ++nt)
                    acc[mt][nt] = __builtin_amdgcn_mfma_f32_16x16x32_bf16(
                        af[mt], bf[nt], acc[mt][nt], 0, 0, 0);
        }
    }

    const int mbase = mg0 + wm * 64 + quad * 4;   // even
    const int fbase = fg0 + wn * 64 + r0;
    #pragma unroll
    for (int nt = 0; nt < 4; ++nt) {
        const int f = fbase + nt * 16;
        if (f >= FRAMES) continue;
        #pragma unroll
        for (int mt = 0; mt < 4; ++mt) {
            const int mrow = mbase + mt * 16;
            const floatx4 v = acc[mt][nt];
            #pragma unroll
            for (int p = 0; p < 2; ++p) {
                const int bin = (mrow + 2 * p) >> 1;
                float2 val;
                val.x = v[2 * p];      // cos
                val.y = v[2 * p + 1];  // sin
                *(float2*)(out + (((size_t)b * NBINS + bin) * FRAMES + f) * 2) = val;
            }
        }
    }
}

extern "C" void kernel_launch(void* const* d_in, const int* in_sizes, int n_in,
                              void* d_out, int out_size, void* d_ws, size_t ws_size,
                              hipStream_t stream) {
    const float* x     = (const float*)d_in[0];
    const float* basis = (const float*)d_in[1];
    float* out         = (float*)d_out;

    unsigned short* basis_bf = (unsigned short*)d_ws;
    unsigned short* xp_bf    = (unsigned short*)d_ws + WS_XP_OFF;

    stft_prep<<<dim3(PREP_BLOCKS), dim3(256), 0, stream>>>(x, basis, basis_bf, xp_bf, out);

    dim3 grid(4, 8, B_SZ);   // 4 frame-tiles x 8 row-tiles x 32 batches = 1024 blocks
    stft_mfma_kernel<<<grid, dim3(256), 0, stream>>>(basis_bf, xp_bf, out);
}

// Round 6
// 126.945 us; speedup vs baseline: 1.0416x; 1.0416x over previous
//
#include <hip/hip_runtime.h>

#define B_SZ   32
#define T_LEN  160000
#define NFFT   1024
#define HOP    320
#define FRAMES 501
#define NBINS  513
#define PADL   512

#define MROWS_BF  1024                    // interleaved cos/sin rows staged as bf16 (bins 0..511)
#define XP_STRIDE 164864                  // padded per-batch xp length (elements)
#define WS_XP_OFF (MROWS_BF * NFFT)       // ushort-element offset of xp region in ws
#define XP_G8_PB  (XP_STRIDE / 8)         // 20608 8-elem groups per batch

// prep-kernel block ranges
#define PB_BASIS  512                     // basis convert (131072 thr x 8 elems)
#define PB_XP     2576                    // xp convert    (659456 thr x 8 elems)
#define PB_BIN512 4012                    // bin512        (16048 waves >= 16032 dots)
#define PREP_BLOCKS (PB_BASIS + PB_XP + PB_BIN512)

typedef __bf16 bf16x8  __attribute__((ext_vector_type(8)));
typedef float  floatx4 __attribute__((ext_vector_type(4)));

__device__ __forceinline__ unsigned short f2bf(float f) {
    unsigned u = __builtin_bit_cast(unsigned, f);
    u += 0x7FFFu + ((u >> 16) & 1u);      // round-to-nearest-even
    return (unsigned short)(u >> 16);
}

__device__ __forceinline__ void gl_lds16(const void* g, void* l) {
    __builtin_amdgcn_global_load_lds(
        (const __attribute__((address_space(1))) unsigned int*)g,
        (__attribute__((address_space(3))) unsigned int*)l, 16, 0, 0);
}

// ---- fused prep (verified R5): basis->bf16 | x->padded bf16 xp | bin512 fp32 ----
__global__ void stft_prep(const float* __restrict__ x,
                          const float* __restrict__ basis,
                          unsigned short* __restrict__ basisb,
                          unsigned short* __restrict__ xpb,
                          float* __restrict__ out) {
    const int blk = blockIdx.x;
    const int tid = threadIdx.x;

    if (blk < PB_BASIS) {
        const int gid = blk * 256 + tid;          // 8 elems per thread, exact cover
        const int row = gid >> 7;                 // 0..1023
        const int col = (gid & 127) * 8;
        const int j = row >> 1, c = row & 1;
        const float* src = basis + (size_t)(j + c * NBINS) * NFFT + col;
        const float4 v0 = *(const float4*)(src);
        const float4 v1 = *(const float4*)(src + 4);
        ushort4 o0, o1;
        o0.x = f2bf(v0.x); o0.y = f2bf(v0.y); o0.z = f2bf(v0.z); o0.w = f2bf(v0.w);
        o1.x = f2bf(v1.x); o1.y = f2bf(v1.y); o1.z = f2bf(v1.z); o1.w = f2bf(v1.w);
        unsigned short* d = basisb + ((size_t)row << 10) + col;
        *(ushort4*)(d)     = o0;
        *(ushort4*)(d + 4) = o1;
    } else if (blk < PB_BASIS + PB_XP) {
        const int i   = (blk - PB_BASIS) * 256 + tid;   // 0..659455, exact cover
        const int b   = i / XP_G8_PB;
        const int pos = (i - b * XP_G8_PB) * 8;         // boundaries (512,160512) are %8==0
        ushort4 o0 = {0,0,0,0}, o1 = {0,0,0,0};
        if (pos >= PADL && pos < T_LEN + PADL) {
            const float* src = x + (size_t)b * T_LEN + (pos - PADL);
            const float4 v0 = *(const float4*)(src);
            const float4 v1 = *(const float4*)(src + 4);
            o0.x = f2bf(v0.x); o0.y = f2bf(v0.y); o0.z = f2bf(v0.z); o0.w = f2bf(v0.w);
            o1.x = f2bf(v1.x); o1.y = f2bf(v1.y); o1.z = f2bf(v1.z); o1.w = f2bf(v1.w);
        }
        unsigned short* d = xpb + (size_t)b * XP_STRIDE + pos;
        *(ushort4*)(d)     = o0;
        *(ushort4*)(d + 4) = o1;
    } else {
        const int lane = tid & 63;
        const int d    = (blk - PB_BASIS - PB_XP) * 4 + (tid >> 6);  // wave-dot id
        if (d >= B_SZ * FRAMES) return;                              // wave-uniform
        const int b = d / FRAMES;
        const int f = d - b * FRAMES;
        const float* br = basis + (size_t)512 * NFFT + lane * 16;
        const float* xb = x + (size_t)b * T_LEN;
        const int base = f * HOP - PADL + lane * 16;
        float sum = 0.f;
        #pragma unroll
        for (int c = 0; c < 4; ++c) {
            const int xi = base + c * 4;
            const float4 bv = *(const float4*)(br + c * 4);
            float4 v;
            if (xi >= 0 && xi + 3 < T_LEN) {
                v = *(const float4*)(xb + xi);
            } else {
                v.x = (xi + 0 >= 0 && xi + 0 < T_LEN) ? xb[xi + 0] : 0.f;
                v.y = (xi + 1 >= 0 && xi + 1 < T_LEN) ? xb[xi + 1] : 0.f;
                v.z = (xi + 2 >= 0 && xi + 2 < T_LEN) ? xb[xi + 2] : 0.f;
                v.w = (xi + 3 >= 0 && xi + 3 < T_LEN) ? xb[xi + 3] : 0.f;
            }
            sum += bv.x * v.x + bv.y * v.y + bv.z * v.z + bv.w * v.w;
        }
        #pragma unroll
        for (int off = 32; off >= 1; off >>= 1) sum += __shfl_down(sum, off);
        if (lane == 0) {
            float2 val; val.x = sum; val.y = 0.f;
            *(float2*)(out + (((size_t)b * NBINS + 512) * FRAMES + f) * 2) = val;
        }
    }
}

// ---- MFMA GEMM: 256x128 tile, 512 threads (8 waves of 64x64), BK=64 as 2x32 panels ----
__launch_bounds__(512, 4)
__global__ void stft_mfma_kernel(const unsigned short* __restrict__ basisb,
                                 const unsigned short* __restrict__ xpb,
                                 float* __restrict__ out) {
    __shared__ unsigned short lsA[2][256 * 32];   // 32 KB: A rows (basis), 64 B rows
    __shared__ unsigned short lsB[2][128 * 32];   // 16 KB: B rows (frames), 64 B rows

    const int tid  = threadIdx.x;
    const int lane = tid & 63;
    const int w    = tid >> 6;        // wave 0..7
    const int wm   = w & 3;           // m-quarter of 256
    const int wn   = w >> 2;          // n-half of 128
    const int r0   = lane & 15;
    const int quad = lane >> 4;

    const int fg0 = blockIdx.x * 128;           // frame tile base (0,128,256,384)
    const int mg0 = blockIdx.y * 256;           // row tile base (0,256,512,768)
    const int b   = blockIdx.z;

    const unsigned short* xpbb = xpb + (size_t)b * XP_STRIDE;

    floatx4 acc[4][4] = {};

    for (int k0 = 0; k0 < NFFT; k0 += 64) {
        __syncthreads();

        #pragma unroll
        for (int h = 0; h < 2; ++h) {
            // A: 256 rows x 32 k = 1024 x 16 B -> 2 issues/thread
            #pragma unroll
            for (int i = 0; i < 2; ++i) {
                const int idx = i * 512 + tid;       // 0..1023
                const int mm  = idx >> 2;            // 0..255
                const int ko  = (idx & 3) * 8;       // 0,8,16,24
                gl_lds16(basisb + (((size_t)(mg0 + mm)) << 10) + k0 + h * 32 + ko,
                         &lsA[h][idx * 8]);
            }
            // B: 128 rows x 32 k = 512 x 16 B -> 1 issue/thread
            {
                const int idx = tid;                 // 0..511
                const int mm  = idx >> 2;            // 0..127
                const int ko  = (idx & 3) * 8;
                gl_lds16(xpbb + (size_t)(fg0 + mm) * HOP + k0 + h * 32 + ko,
                         &lsB[h][idx * 8]);
            }
        }
        __syncthreads();

        #pragma unroll
        for (int h = 0; h < 2; ++h) {
            bf16x8 af[4], bf[4];
            #pragma unroll
            for (int mt = 0; mt < 4; ++mt)
                af[mt] = *(const bf16x8*)(&lsA[h][(wm * 64 + mt * 16 + r0) * 32 + quad * 8]);
            #pragma unroll
            for (int nt = 0; nt < 4; ++nt)
                bf[nt] = *(const bf16x8*)(&lsB[h][(wn * 64 + nt * 16 + r0) * 32 + quad * 8]);

            #pragma unroll
            for (int mt = 0; mt < 4; ++mt)
                #pragma unroll
                for (int nt = 0; nt < 4; ++nt)
                    acc[mt][nt] = __builtin_amdgcn_mfma_f32_16x16x32_bf16(
                        af[mt], bf[nt], acc[mt][nt], 0, 0, 0);
        }
    }

    // epilogue: rows are interleaved (cos,sin) pairs -> coalesced float2 stores
    const int mbase = mg0 + wm * 64 + quad * 4;   // even
    const int fbase = fg0 + wn * 64 + r0;
    #pragma unroll
    for (int nt = 0; nt < 4; ++nt) {
        const int f = fbase + nt * 16;
        if (f >= FRAMES) continue;
        #pragma unroll
        for (int mt = 0; mt < 4; ++mt) {
            const int mrow = mbase + mt * 16;
            const floatx4 v = acc[mt][nt];
            #pragma unroll
            for (int p = 0; p < 2; ++p) {
                const int bin = (mrow + 2 * p) >> 1;
                float2 val;
                val.x = v[2 * p];      // cos
                val.y = v[2 * p + 1];  // sin
                *(float2*)(out + (((size_t)b * NBINS + bin) * FRAMES + f) * 2) = val;
            }
        }
    }
}

extern "C" void kernel_launch(void* const* d_in, const int* in_sizes, int n_in,
                              void* d_out, int out_size, void* d_ws, size_t ws_size,
                              hipStream_t stream) {
    const float* x     = (const float*)d_in[0];
    const float* basis = (const float*)d_in[1];
    float* out         = (float*)d_out;

    unsigned short* basis_bf = (unsigned short*)d_ws;
    unsigned short* xp_bf    = (unsigned short*)d_ws + WS_XP_OFF;

    stft_prep<<<dim3(PREP_BLOCKS), dim3(256), 0, stream>>>(x, basis, basis_bf, xp_bf, out);

    dim3 grid(4, 4, B_SZ);   // 4 frame-tiles x 4 row-tiles x 32 batches = 512 blocks (2/CU)
    stft_mfma_kernel<<<grid, dim3(512), 0, stream>>>(basis_bf, xp_bf, out);
}